// Round 16
// baseline (245.825 us; speedup 1.0000x reference)
//
#include <hip/hip_runtime.h>
#include <math.h>

#define NEG_SLOPE 0.2f
#define MAXDEG 64   // max in-degree incl self-loop; Poisson(17) over N=50K -> max ~37, P(>63) ~ 1e-19

typedef _Float16 hv2 __attribute__((ext_vector_type(2)));
typedef _Float16 hv8 __attribute__((ext_vector_type(8)));
typedef unsigned short usv4 __attribute__((ext_vector_type(4)));

static __device__ __forceinline__ float leaky(float v){ return v > 0.f ? v : NEG_SLOPE * v; }
static __device__ __forceinline__ float eluf(float v){ return v > 0.f ? v : expm1f(v); }
static __device__ __forceinline__ float eluf_fast(float v){ return v > 0.f ? v : __expf(v) - 1.f; }

// ---------------- CSR build: ONE atomic pass, fixed-stride buckets (r9, -43us) ----------------
// r16: single-pass, NO XCD partitioning. The old slot-filter made all 8 slot
// groups read the ENTIRE edge list (8x 6.8 MB) to keep atomics XCD-local; but
// gemm2 evicts L2 between scatter and aggr2 anyway, so locality bought nothing.
// Each thread owns one edge: 1x reads, device-scope atomic, 2B store.
__global__ void __launch_bounds__(256) scatter_k(const int* __restrict__ esrc, const int* __restrict__ edst,
                                                 int* __restrict__ cnt, unsigned short* __restrict__ csr,
                                                 int Eg, int Etot, int N){
  const int stride = gridDim.x * blockDim.x;
  for (int e = blockIdx.x * blockDim.x + threadIdx.x; e < Etot; e += stride){
    int s, d;
    if (e < Eg){ d = edst[e]; s = esrc[e]; }
    else { s = d = e - Eg; }
    int pos = atomicAdd(&cnt[d], 1);
    if (pos < MAXDEG) csr[((size_t)d << 6) + pos] = (unsigned short)s;
  }
}

// ---------------- layer 1 + layer 2 dense, FUSED (r13 base, r15 rework) ----------------
// r15: (a) W staged ONCE as fp16 k-pairs (32KB LDS) -> 8-phase dbuf + 7 barriers
// deleted; (b) act1 stored as fp16 k-pairs; inner loop = v_dot2_f32_f16
// (2 MAC/op, fp32 accum) -> ~2.5x fewer VALU ops than convert+fma.
__global__ void __launch_bounds__(256) gemm2_k(const int* __restrict__ cnt, const unsigned short* __restrict__ csr,
                                               const float* __restrict__ x,
                                               const float* __restrict__ as1, const float* __restrict__ ad1,
                                               const float* __restrict__ W1f, const float* __restrict__ b1f,
                                               const float* __restrict__ W,
                                               const float* __restrict__ a_s, const float* __restrict__ a_d,
                                               _Float16* __restrict__ hh, float* __restrict__ as_, float* __restrict__ ad_,
                                               int N){
  __shared__ hv2 sAh[64][68];          // [kpair][node] act1 fp16 pairs, 17.4 KB
  __shared__ hv2 sWh[64][128];         // [kpair][col] W fp16 pairs, 32 KB
  __shared__ float sR[64][4];          // per-node per-head softmax ratio r
  __shared__ float sDot[8];            // dA[0..3], dD[0..3]
  const int t = threadIdx.x;
  const int n0 = blockIdx.x * 64;
  const int tx = t & 15, ty = t >> 4;
  const int c0 = tx * 8, r0 = ty * 4;

  // --- fused dots1 (redundant per block) ---
  if (t < 128){
    float ps = W1f[t] * as1[t];
    float pd = W1f[t] * ad1[t];
    #pragma unroll
    for (int off = 16; off; off >>= 1){
      ps += __shfl_xor(ps, off, 32);
      pd += __shfl_xor(pd, off, 32);
    }
    if ((t & 31) == 0){ sDot[t >> 5] = ps; sDot[4 + (t >> 5)] = pd; }
  }
  __syncthreads();

  // --- stage ALL of W as k-pairs: thread handles kpair pk = pass*8 + (t>>5), cols wq*4..+3 ---
  {
    const int pk0 = t >> 5;        // 0..7
    const int wq  = t & 31;        // col quad
    #pragma unroll 1
    for (int pass = 0; pass < 8; ++pass){
      const int pk = pass * 8 + pk0;
      float4 rw0 = *(const float4*)&W[(size_t)(2 * pk)     * 128 + wq * 4];
      float4 rw1 = *(const float4*)&W[(size_t)(2 * pk + 1) * 128 + wq * 4];
      sWh[pk][wq * 4 + 0] = hv2{(_Float16)rw0.x, (_Float16)rw1.x};
      sWh[pk][wq * 4 + 1] = hv2{(_Float16)rw0.y, (_Float16)rw1.y};
      sWh[pk][wq * 4 + 2] = hv2{(_Float16)rw0.z, (_Float16)rw1.z};
      sWh[pk][wq * 4 + 3] = hv2{(_Float16)rw0.w, (_Float16)rw1.w};
    }
  }

  // --- fused r1: 4 lanes/node split the edges, all heads per lane (r6 idx rotation, r13) ---
  {
    const int nl2 = t >> 2, q = t & 3;
    const int gn = n0 + nl2;
    if (gn < N){
      const float xd = x[gn];
      const float dA0 = sDot[0], dA1 = sDot[1], dA2 = sDot[2], dA3 = sDot[3];
      const float e0d = xd * sDot[4], e1d = xd * sDot[5], e2d = xd * sDot[6], e3d = xd * sDot[7];
      const int start = gn << 6;
      int dg = cnt[gn]; dg = dg < MAXDEG ? dg : MAXDEG;
      const int endi = start + dg;
      float s0 = 0.f, s1 = 0.f, s2 = 0.f, s3 = 0.f;
      float t0 = 0.f, t1 = 0.f, t2 = 0.f, t3 = 0.f;
      int i = start + q;
      if (i < endi){
        int idx = csr[i];
        while (true){
          const int inext = i + 4;
          const bool more = inext < endi;
          const int idxn = csr[more ? inext : i];   // clamped prefetch, branchless
          float xs = x[idx];
          float p0 = __expf(leaky(xs * dA0 + e0d));
          float p1 = __expf(leaky(xs * dA1 + e1d));
          float p2 = __expf(leaky(xs * dA2 + e2d));
          float p3 = __expf(leaky(xs * dA3 + e3d));
          s0 += p0; s1 += p1; s2 += p2; s3 += p3;
          t0 += p0 * xs; t1 += p1 * xs; t2 += p2 * xs; t3 += p3 * xs;
          if (!more) break;
          idx = idxn; i = inext;
        }
      }
      #pragma unroll
      for (int off = 2; off; off >>= 1){
        s0 += __shfl_xor(s0, off, 4); t0 += __shfl_xor(t0, off, 4);
        s1 += __shfl_xor(s1, off, 4); t1 += __shfl_xor(t1, off, 4);
        s2 += __shfl_xor(s2, off, 4); t2 += __shfl_xor(t2, off, 4);
        s3 += __shfl_xor(s3, off, 4); t3 += __shfl_xor(t3, off, 4);
      }
      float sq = (q == 0) ? s0 : (q == 1) ? s1 : (q == 2) ? s2 : s3;
      float tq = (q == 0) ? t0 : (q == 1) ? t1 : (q == 2) ? t2 : t3;
      sR[nl2][q] = tq / sq;
    }
  }
  __syncthreads();

  // stage act1 tile as fp16 k-pairs: nl = t&63 (node), q = t>>6 (head, wave-uniform)
  {
    const int nl = t & 63, q = t >> 6;
    const int gn = n0 + nl;
    const bool valid = (gn < N);
    float r = valid ? sR[nl][q] : 0.f;
    #pragma unroll
    for (int j = 0; j < 16; ++j){
      const int c = q * 32 + 2 * j;       // wave-uniform -> scalar W1/b1 loads
      float v0 = eluf_fast(W1f[c]     * r + b1f[c]);
      float v1 = eluf_fast(W1f[c + 1] * r + b1f[c + 1]);
      sAh[c >> 1][nl] = valid ? hv2{(_Float16)v0, (_Float16)v1} : hv2{(_Float16)0.f, (_Float16)0.f};
    }
  }

  float acc[4][8];
  #pragma unroll
  for (int r = 0; r < 4; ++r)
    #pragma unroll
    for (int c = 0; c < 8; ++c) acc[r][c] = 0.f;

  __syncthreads();

  // ---- K=128 main loop: 64 k-pairs, NO barriers, dot2 inner ----
  #pragma unroll 1
  for (int tile = 0; tile < 8; ++tile){
    #pragma unroll
    for (int k8 = 0; k8 < 8; ++k8){
      const int kp = tile * 8 + k8;
      hv8 av = *(const hv8*)&sAh[kp][r0];       // 4 node-pairs (16B)
      hv8 wv0 = *(const hv8*)&sWh[kp][c0];      // cols c0..c0+3 (16B)
      hv8 wv1 = *(const hv8*)&sWh[kp][c0 + 4];  // cols c0+4..c0+7 (16B)
      hv2 a[4], w[8];
      #pragma unroll
      for (int r = 0; r < 4; ++r) a[r] = hv2{av[2*r], av[2*r+1]};
      #pragma unroll
      for (int c = 0; c < 4; ++c) w[c] = hv2{wv0[2*c], wv0[2*c+1]};
      #pragma unroll
      for (int c = 0; c < 4; ++c) w[4+c] = hv2{wv1[2*c], wv1[2*c+1]};
      #pragma unroll
      for (int r = 0; r < 4; ++r)
        #pragma unroll
        for (int c = 0; c < 8; ++c)
          acc[r][c] = __builtin_amdgcn_fdot2(a[r], w[c], acc[r][c], false);
    }
  }

  float asv[8], adv[8];
  #pragma unroll
  for (int c = 0; c < 8; ++c){ asv[c] = a_s[c0 + c]; adv[c] = a_d[c0 + c]; }

  const int hd  = tx >> 2;            // head of this column group
  const int off = (tx & 3) * 8;       // channel offset within head

  #pragma unroll
  for (int r = 0; r < 4; ++r){
    int n = n0 + r0 + r;
    if (n >= N) continue;
    hv8 hv;
    #pragma unroll
    for (int c = 0; c < 8; ++c) hv[c] = (_Float16)acc[r][c];
    *(hv8*)&hh[((size_t)hd * N + n) * 32 + off] = hv;
    float ps = 0.f, pd = 0.f;
    #pragma unroll
    for (int c = 0; c < 8; ++c){ ps += acc[r][c] * asv[c]; pd += acc[r][c] * adv[c]; }
    ps += __shfl_xor(ps, 1); ps += __shfl_xor(ps, 2);
    pd += __shfl_xor(pd, 1); pd += __shfl_xor(pd, 2);
    if ((tx & 3) == 0){
      as_[(size_t)hd * N + n] = ps;   // head-major
      ad_[(size_t)hd * N + n] = pd;
    }
  }
}

// ---- layer-2 aggregate + fused layer-3 transform ----
// 4 lanes/node; two nodes per lane-group (r8). Bucket addressing (r9).
// Split-ash + quad-broadcast (r10, mild +). At its TA/latency floor (r1-r10 probes).
__global__ void __launch_bounds__(256) node_aggr2_k(const int* __restrict__ cnt, const unsigned short* __restrict__ csr,
                                                    const float* __restrict__ as_, const float* __restrict__ ad_,
                                                    const _Float16* __restrict__ hh, const float* __restrict__ b2,
                                                    const float* __restrict__ W3, float* __restrict__ h3, int N){
  const int slot   = blockIdx.x & 7;
  const int chunk  = blockIdx.x >> 3;
  const int head   = slot >> 1;
  const int parity = slot & 1;
  const int t  = threadIdx.x;
  const int nl = t >> 2;          // node slot 0..63
  const int q  = t & 3;           // lane within node
  const int base = chunk * 256 + parity * 128 + nl;
  const float* __restrict__ ash = as_ + (size_t)head * N;
  const _Float16* __restrict__ hhh = hh + (size_t)head * N * 32 + q * 8;
  const int c0 = head * 32 + q * 8;

  #pragma unroll 1
  for (int half = 0; half < 2; ++half){
    const int node = base + half * 64;
    if (node >= N) continue;
    const int start = node << 6;
    int dg = cnt[node]; dg = dg < MAXDEG ? dg : MAXDEG;
    const int end = start + dg;
    const float adv = ad_[(size_t)head * N + node];

    float s = 0.f;
    float acc[8] = {0.f, 0.f, 0.f, 0.f, 0.f, 0.f, 0.f, 0.f};
    int i = start;

    // main: 4 edges/iter, rotated index prefetch (start is 4-aligned)
    const int iend4 = start + (dg & ~3);
    if (i < iend4){
      usv4 ia = *(const usv4*)&csr[i];
      while (i < iend4){
        const int inext = i + 4;
        const int ipf = (inext < iend4) ? inext : i;   // clamped, branchless
        usv4 ib = *(const usv4*)&csr[ipf];
        const int sx = ia.x, sy = ia.y, sz = ia.z, sw = ia.w;
        // own-edge ash load (1 gather/lane instead of 4)
        const int mysrc = (q == 0) ? sx : (q == 1) ? sy : (q == 2) ? sz : sw;
        float aq = ash[mysrc];
        hv8 h0 = *(const hv8*)&hhh[(size_t)sx * 32];
        hv8 h1 = *(const hv8*)&hhh[(size_t)sy * 32];
        hv8 h2 = *(const hv8*)&hhh[(size_t)sz * 32];
        hv8 h3v = *(const hv8*)&hhh[(size_t)sw * 32];
        float pq = __expf(leaky(aq + adv));
        // quad-broadcast p0..p3 to all 4 lanes of the group
        float p0 = __shfl(pq, 0, 4);
        float p1 = __shfl(pq, 1, 4);
        float p2 = __shfl(pq, 2, 4);
        float p3 = __shfl(pq, 3, 4);
        s += (p0 + p1) + (p2 + p3);
        #pragma unroll
        for (int c = 0; c < 8; ++c)
          acc[c] += (float)h0[c]*p0 + (float)h1[c]*p1 + (float)h2[c]*p2 + (float)h3v[c]*p3;
        ia = ib; i = inext;
      }
    }
    // tail (<=3 edges): all lanes load same ash, as before
    for (; i < end; ++i){
      int src = csr[i];
      float p = __expf(leaky(ash[src] + adv));
      hv8 hv = *(const hv8*)&hhh[(size_t)src * 32];
      s += p;
      #pragma unroll
      for (int c = 0; c < 8; ++c) acc[c] += (float)hv[c] * p;
    }

    const float inv = 1.f / s;
    // act2 slice + fused layer-3 partial dot (eluf_fast: abs err ~1e-5)
    float part = 0.f;
    #pragma unroll
    for (int c = 0; c < 8; ++c){
      float v = eluf_fast(acc[c] * inv + b2[c0 + c]);
      part += v * W3[c0 + c];
    }
    part += __shfl_xor(part, 1, 4);
    part += __shfl_xor(part, 2, 4);
    if (q == 0) unsafeAtomicAdd(&h3[node], part);
  }
}

// layer-3 aggregate: e computed inline from h3. 8 lanes/node.
// Index-prefetch rotation (r6) + bucket addressing (r9).
__global__ void __launch_bounds__(256) node_aggr3_k(const int* __restrict__ cnt, const unsigned short* __restrict__ csr,
                                                    const float* __restrict__ h3,
                                                    const float* __restrict__ a_s3, const float* __restrict__ a_d3,
                                                    const float* __restrict__ b3,
                                                    float* __restrict__ out, int N){
  int node = blockIdx.x * 32 + (threadIdx.x >> 3);
  if (node >= N) return;
  int q = threadIdx.x & 7;
  const int start = node << 6;
  int dg = cnt[node]; dg = dg < MAXDEG ? dg : MAXDEG;
  const int end = start + dg;
  const float a_s3v = a_s3[0];
  const float adv = a_d3[0] * h3[node];
  float s = 0.f, acc = 0.f;
  int i = start + q;
  if (i < end){
    int idx = csr[i];
    while (true){
      const int inext = i + 8;
      const bool more = inext < end;
      const int idxn = csr[more ? inext : i];
      float hv = h3[idx];
      float p = __expf(leaky(a_s3v * hv + adv));
      s += p; acc += hv * p;
      if (!more) break;
      idx = idxn; i = inext;
    }
  }
  #pragma unroll
  for (int off = 4; off; off >>= 1){
    s += __shfl_xor(s, off, 8);
    acc += __shfl_xor(acc, off, 8);
  }
  if (q == 0) out[node] = acc / s + b3[0];
}

// ---------------- launch ----------------
extern "C" void kernel_launch(void* const* d_in, const int* in_sizes, int n_in,
                              void* d_out, int out_size, void* d_ws, size_t ws_size,
                              hipStream_t stream){
  const float* x   = (const float*)d_in[0];
  const int*   ei  = (const int*)  d_in[1];
  const float* W1  = (const float*)d_in[2];
  const float* as1 = (const float*)d_in[3];
  const float* ad1 = (const float*)d_in[4];
  const float* b1  = (const float*)d_in[5];
  const float* W2  = (const float*)d_in[6];
  const float* as2 = (const float*)d_in[7];
  const float* ad2 = (const float*)d_in[8];
  const float* b2  = (const float*)d_in[9];
  const float* W3  = (const float*)d_in[10];
  const float* as3 = (const float*)d_in[11];
  const float* ad3 = (const float*)d_in[12];
  const float* b3  = (const float*)d_in[13];

  const int N    = in_sizes[0];       // IN_C = 1; N < 65536 required (ushort csr)
  const int Eg   = in_sizes[1] / 2;
  const int Etot = Eg + N;
  const int* esrc = ei;
  const int* edst = ei + Eg;

  char* w = (char*)d_ws;
  auto carve = [&](size_t bytes)->char*{
    char* p = w; w += (bytes + 15) & ~size_t(15); return p;
  };
  _Float16* hbuf = (_Float16*)carve((size_t)N * 128 * 2);  // fp16 head-major [4][N][32]
  float* asb    = (float*)carve((size_t)N * 4 * 4);   // head-major [4][N]
  float* adb    = (float*)carve((size_t)N * 4 * 4);   // head-major [4][N]
  float* h3b    = (float*)carve((size_t)N * 4);
  int*   cnt    = (int*)  carve((size_t)N * 4);
  unsigned short* csr16 = (unsigned short*)carve((size_t)N * MAXDEG * 2);  // bucketed

  const int B = 256;
  auto cdiv = [](int a, int b){ return (a + b - 1) / b; };

  // ---- CSR build: single atomic pass into fixed-stride buckets (r16: no slot filter) ----
  hipMemsetAsync(cnt, 0, (size_t)N * 4, stream);
  hipMemsetAsync(h3b, 0, (size_t)N * 4, stream);
  scatter_k<<<1024, B, 0, stream>>>(esrc, edst, cnt, csr16, Eg, Etot, N);

  // ---- layers 1+2 fused: W staged once + r-prologue + dot2 matmul (no mid-loop barriers) ----
  gemm2_k<<<cdiv(N, 64), B, 0, stream>>>(cnt, csr16, x, as1, ad1, W1, b1,
                                         W2, as2, ad2, hbuf, asb, adb, N);
  // aggregate + fused layer-3 transform (writes h3 via atomics)
  node_aggr2_k<<<cdiv(N, 256) * 8, B, 0, stream>>>(cnt, csr16, asb, adb,
                                                   hbuf, b2, W3, h3b, N);

  // ---- layer 3 aggregate (H=1, C=1) ----
  node_aggr3_k<<<cdiv(N, 32), B, 0, stream>>>(cnt, csr16, h3b, as3, ad3, b3, (float*)d_out, N);
}

// Round 18
// 220.384 us; speedup vs baseline: 1.1154x; 1.1154x over previous
//
#include <hip/hip_runtime.h>
#include <math.h>

#define NEG_SLOPE 0.2f
#define MAXDEG 64   // max in-degree incl self-loop; Poisson(17) over N=50K -> max ~37, P(>63) ~ 1e-19

typedef _Float16 hv2 __attribute__((ext_vector_type(2)));
typedef _Float16 hv8 __attribute__((ext_vector_type(8)));
typedef unsigned short usv4 __attribute__((ext_vector_type(4)));

static __device__ __forceinline__ float leaky(float v){ return v > 0.f ? v : NEG_SLOPE * v; }
static __device__ __forceinline__ float eluf(float v){ return v > 0.f ? v : expm1f(v); }
static __device__ __forceinline__ float eluf_fast(float v){ return v > 0.f ? v : __expf(v) - 1.f; }

// ---------------- CSR build: ONE atomic pass, fixed-stride buckets (r9) ----------------
// XCD-range-partitioned: each slot group filters to its own N/8 destination
// range so atomics + 2B bucket stores stay XCD-L2-local and coalesce before
// eviction. r16's unpartitioned probe: WRITE_SIZE 3->46 MB, dur 25->68 us
// (cross-XCD line ping-pong). Partition by destination, replicate the reads.
__global__ void __launch_bounds__(256) scatter_k(const int* __restrict__ esrc, const int* __restrict__ edst,
                                                 int* __restrict__ cnt, unsigned short* __restrict__ csr,
                                                 int Eg, int Etot, int N){
  const int slot = blockIdx.x & 7;
  const int lo = (int)(((long long)slot * N) >> 3);
  const int hi = (int)(((long long)(slot + 1) * N) >> 3);
  const int stride = (gridDim.x >> 3) * blockDim.x;
  for (int e = (blockIdx.x >> 3) * blockDim.x + threadIdx.x; e < Etot; e += stride){
    int s, d;
    if (e < Eg){ d = edst[e]; if (d < lo || d >= hi) continue; s = esrc[e]; }
    else { s = d = e - Eg; if (d < lo || d >= hi) continue; }
    int pos = atomicAdd(&cnt[d], 1);
    if (pos < MAXDEG) csr[((size_t)d << 6) + pos] = (unsigned short)s;
  }
}

// ---------------- layer 1 + layer 2 dense, FUSED (r13 base, r15 rework) ----------------
// r15: (a) W staged ONCE as fp16 k-pairs (32KB LDS) -> 8-phase dbuf + 7 barriers
// deleted; (b) act1 stored as fp16 k-pairs; inner loop = v_dot2_f32_f16
// (2 MAC/op, fp32 accum) -> ~2.5x fewer VALU ops than convert+fma.
__global__ void __launch_bounds__(256) gemm2_k(const int* __restrict__ cnt, const unsigned short* __restrict__ csr,
                                               const float* __restrict__ x,
                                               const float* __restrict__ as1, const float* __restrict__ ad1,
                                               const float* __restrict__ W1f, const float* __restrict__ b1f,
                                               const float* __restrict__ W,
                                               const float* __restrict__ a_s, const float* __restrict__ a_d,
                                               _Float16* __restrict__ hh, float* __restrict__ as_, float* __restrict__ ad_,
                                               int N){
  __shared__ hv2 sAh[64][68];          // [kpair][node] act1 fp16 pairs, 17.4 KB
  __shared__ hv2 sWh[64][128];         // [kpair][col] W fp16 pairs, 32 KB
  __shared__ float sR[64][4];          // per-node per-head softmax ratio r
  __shared__ float sDot[8];            // dA[0..3], dD[0..3]
  const int t = threadIdx.x;
  const int n0 = blockIdx.x * 64;
  const int tx = t & 15, ty = t >> 4;
  const int c0 = tx * 8, r0 = ty * 4;

  // --- fused dots1 (redundant per block) ---
  if (t < 128){
    float ps = W1f[t] * as1[t];
    float pd = W1f[t] * ad1[t];
    #pragma unroll
    for (int off = 16; off; off >>= 1){
      ps += __shfl_xor(ps, off, 32);
      pd += __shfl_xor(pd, off, 32);
    }
    if ((t & 31) == 0){ sDot[t >> 5] = ps; sDot[4 + (t >> 5)] = pd; }
  }
  __syncthreads();

  // --- stage ALL of W as k-pairs: thread handles kpair pk = pass*8 + (t>>5), cols wq*4..+3 ---
  {
    const int pk0 = t >> 5;        // 0..7
    const int wq  = t & 31;        // col quad
    #pragma unroll 1
    for (int pass = 0; pass < 8; ++pass){
      const int pk = pass * 8 + pk0;
      float4 rw0 = *(const float4*)&W[(size_t)(2 * pk)     * 128 + wq * 4];
      float4 rw1 = *(const float4*)&W[(size_t)(2 * pk + 1) * 128 + wq * 4];
      sWh[pk][wq * 4 + 0] = hv2{(_Float16)rw0.x, (_Float16)rw1.x};
      sWh[pk][wq * 4 + 1] = hv2{(_Float16)rw0.y, (_Float16)rw1.y};
      sWh[pk][wq * 4 + 2] = hv2{(_Float16)rw0.z, (_Float16)rw1.z};
      sWh[pk][wq * 4 + 3] = hv2{(_Float16)rw0.w, (_Float16)rw1.w};
    }
  }

  // --- fused r1: 4 lanes/node split the edges, all heads per lane (r6 idx rotation, r13) ---
  {
    const int nl2 = t >> 2, q = t & 3;
    const int gn = n0 + nl2;
    if (gn < N){
      const float xd = x[gn];
      const float dA0 = sDot[0], dA1 = sDot[1], dA2 = sDot[2], dA3 = sDot[3];
      const float e0d = xd * sDot[4], e1d = xd * sDot[5], e2d = xd * sDot[6], e3d = xd * sDot[7];
      const int start = gn << 6;
      int dg = cnt[gn]; dg = dg < MAXDEG ? dg : MAXDEG;
      const int endi = start + dg;
      float s0 = 0.f, s1 = 0.f, s2 = 0.f, s3 = 0.f;
      float t0 = 0.f, t1 = 0.f, t2 = 0.f, t3 = 0.f;
      int i = start + q;
      if (i < endi){
        int idx = csr[i];
        while (true){
          const int inext = i + 4;
          const bool more = inext < endi;
          const int idxn = csr[more ? inext : i];   // clamped prefetch, branchless
          float xs = x[idx];
          float p0 = __expf(leaky(xs * dA0 + e0d));
          float p1 = __expf(leaky(xs * dA1 + e1d));
          float p2 = __expf(leaky(xs * dA2 + e2d));
          float p3 = __expf(leaky(xs * dA3 + e3d));
          s0 += p0; s1 += p1; s2 += p2; s3 += p3;
          t0 += p0 * xs; t1 += p1 * xs; t2 += p2 * xs; t3 += p3 * xs;
          if (!more) break;
          idx = idxn; i = inext;
        }
      }
      #pragma unroll
      for (int off = 2; off; off >>= 1){
        s0 += __shfl_xor(s0, off, 4); t0 += __shfl_xor(t0, off, 4);
        s1 += __shfl_xor(s1, off, 4); t1 += __shfl_xor(t1, off, 4);
        s2 += __shfl_xor(s2, off, 4); t2 += __shfl_xor(t2, off, 4);
        s3 += __shfl_xor(s3, off, 4); t3 += __shfl_xor(t3, off, 4);
      }
      float sq = (q == 0) ? s0 : (q == 1) ? s1 : (q == 2) ? s2 : s3;
      float tq = (q == 0) ? t0 : (q == 1) ? t1 : (q == 2) ? t2 : t3;
      sR[nl2][q] = tq / sq;
    }
  }
  __syncthreads();

  // stage act1 tile as fp16 k-pairs: nl = t&63 (node), q = t>>6 (head, wave-uniform)
  {
    const int nl = t & 63, q = t >> 6;
    const int gn = n0 + nl;
    const bool valid = (gn < N);
    float r = valid ? sR[nl][q] : 0.f;
    #pragma unroll
    for (int j = 0; j < 16; ++j){
      const int c = q * 32 + 2 * j;       // wave-uniform -> scalar W1/b1 loads
      float v0 = eluf_fast(W1f[c]     * r + b1f[c]);
      float v1 = eluf_fast(W1f[c + 1] * r + b1f[c + 1]);
      sAh[c >> 1][nl] = valid ? hv2{(_Float16)v0, (_Float16)v1} : hv2{(_Float16)0.f, (_Float16)0.f};
    }
  }

  float acc[4][8];
  #pragma unroll
  for (int r = 0; r < 4; ++r)
    #pragma unroll
    for (int c = 0; c < 8; ++c) acc[r][c] = 0.f;

  __syncthreads();

  // ---- K=128 main loop: 64 k-pairs, NO barriers, dot2 inner ----
  #pragma unroll 1
  for (int tile = 0; tile < 8; ++tile){
    #pragma unroll
    for (int k8 = 0; k8 < 8; ++k8){
      const int kp = tile * 8 + k8;
      hv8 av = *(const hv8*)&sAh[kp][r0];       // 4 node-pairs (16B)
      hv8 wv0 = *(const hv8*)&sWh[kp][c0];      // cols c0..c0+3 (16B)
      hv8 wv1 = *(const hv8*)&sWh[kp][c0 + 4];  // cols c0+4..c0+7 (16B)
      hv2 a[4], w[8];
      #pragma unroll
      for (int r = 0; r < 4; ++r) a[r] = hv2{av[2*r], av[2*r+1]};
      #pragma unroll
      for (int c = 0; c < 4; ++c) w[c] = hv2{wv0[2*c], wv0[2*c+1]};
      #pragma unroll
      for (int c = 0; c < 4; ++c) w[4+c] = hv2{wv1[2*c], wv1[2*c+1]};
      #pragma unroll
      for (int r = 0; r < 4; ++r)
        #pragma unroll
        for (int c = 0; c < 8; ++c)
          acc[r][c] = __builtin_amdgcn_fdot2(a[r], w[c], acc[r][c], false);
    }
  }

  float asv[8], adv[8];
  #pragma unroll
  for (int c = 0; c < 8; ++c){ asv[c] = a_s[c0 + c]; adv[c] = a_d[c0 + c]; }

  const int hd  = tx >> 2;            // head of this column group
  const int off = (tx & 3) * 8;       // channel offset within head

  #pragma unroll
  for (int r = 0; r < 4; ++r){
    int n = n0 + r0 + r;
    if (n >= N) continue;
    hv8 hv;
    #pragma unroll
    for (int c = 0; c < 8; ++c) hv[c] = (_Float16)acc[r][c];
    *(hv8*)&hh[((size_t)hd * N + n) * 32 + off] = hv;
    float ps = 0.f, pd = 0.f;
    #pragma unroll
    for (int c = 0; c < 8; ++c){ ps += acc[r][c] * asv[c]; pd += acc[r][c] * adv[c]; }
    ps += __shfl_xor(ps, 1); ps += __shfl_xor(ps, 2);
    pd += __shfl_xor(pd, 1); pd += __shfl_xor(pd, 2);
    if ((tx & 3) == 0){
      as_[(size_t)hd * N + n] = ps;   // head-major
      ad_[(size_t)hd * N + n] = pd;
    }
  }
}

// ---- layer-2 aggregate + fused layer-3 transform ----
// 4 lanes/node; two nodes per lane-group (r8). Bucket addressing (r9).
// Split-ash + quad-broadcast (r10, mild +). At its TA/latency floor (r1-r10 probes).
__global__ void __launch_bounds__(256) node_aggr2_k(const int* __restrict__ cnt, const unsigned short* __restrict__ csr,
                                                    const float* __restrict__ as_, const float* __restrict__ ad_,
                                                    const _Float16* __restrict__ hh, const float* __restrict__ b2,
                                                    const float* __restrict__ W3, float* __restrict__ h3, int N){
  const int slot   = blockIdx.x & 7;
  const int chunk  = blockIdx.x >> 3;
  const int head   = slot >> 1;
  const int parity = slot & 1;
  const int t  = threadIdx.x;
  const int nl = t >> 2;          // node slot 0..63
  const int q  = t & 3;           // lane within node
  const int base = chunk * 256 + parity * 128 + nl;
  const float* __restrict__ ash = as_ + (size_t)head * N;
  const _Float16* __restrict__ hhh = hh + (size_t)head * N * 32 + q * 8;
  const int c0 = head * 32 + q * 8;

  #pragma unroll 1
  for (int half = 0; half < 2; ++half){
    const int node = base + half * 64;
    if (node >= N) continue;
    const int start = node << 6;
    int dg = cnt[node]; dg = dg < MAXDEG ? dg : MAXDEG;
    const int end = start + dg;
    const float adv = ad_[(size_t)head * N + node];

    float s = 0.f;
    float acc[8] = {0.f, 0.f, 0.f, 0.f, 0.f, 0.f, 0.f, 0.f};
    int i = start;

    // main: 4 edges/iter, rotated index prefetch (start is 4-aligned)
    const int iend4 = start + (dg & ~3);
    if (i < iend4){
      usv4 ia = *(const usv4*)&csr[i];
      while (i < iend4){
        const int inext = i + 4;
        const int ipf = (inext < iend4) ? inext : i;   // clamped, branchless
        usv4 ib = *(const usv4*)&csr[ipf];
        const int sx = ia.x, sy = ia.y, sz = ia.z, sw = ia.w;
        // own-edge ash load (1 gather/lane instead of 4)
        const int mysrc = (q == 0) ? sx : (q == 1) ? sy : (q == 2) ? sz : sw;
        float aq = ash[mysrc];
        hv8 h0 = *(const hv8*)&hhh[(size_t)sx * 32];
        hv8 h1 = *(const hv8*)&hhh[(size_t)sy * 32];
        hv8 h2 = *(const hv8*)&hhh[(size_t)sz * 32];
        hv8 h3v = *(const hv8*)&hhh[(size_t)sw * 32];
        float pq = __expf(leaky(aq + adv));
        // quad-broadcast p0..p3 to all 4 lanes of the group
        float p0 = __shfl(pq, 0, 4);
        float p1 = __shfl(pq, 1, 4);
        float p2 = __shfl(pq, 2, 4);
        float p3 = __shfl(pq, 3, 4);
        s += (p0 + p1) + (p2 + p3);
        #pragma unroll
        for (int c = 0; c < 8; ++c)
          acc[c] += (float)h0[c]*p0 + (float)h1[c]*p1 + (float)h2[c]*p2 + (float)h3v[c]*p3;
        ia = ib; i = inext;
      }
    }
    // tail (<=3 edges): all lanes load same ash, as before
    for (; i < end; ++i){
      int src = csr[i];
      float p = __expf(leaky(ash[src] + adv));
      hv8 hv = *(const hv8*)&hhh[(size_t)src * 32];
      s += p;
      #pragma unroll
      for (int c = 0; c < 8; ++c) acc[c] += (float)hv[c] * p;
    }

    const float inv = 1.f / s;
    // act2 slice + fused layer-3 partial dot (eluf_fast: abs err ~1e-5)
    float part = 0.f;
    #pragma unroll
    for (int c = 0; c < 8; ++c){
      float v = eluf_fast(acc[c] * inv + b2[c0 + c]);
      part += v * W3[c0 + c];
    }
    part += __shfl_xor(part, 1, 4);
    part += __shfl_xor(part, 2, 4);
    if (q == 0) unsafeAtomicAdd(&h3[node], part);
  }
}

// layer-3 aggregate: e computed inline from h3. 8 lanes/node.
// Index-prefetch rotation (r6) + bucket addressing (r9).
__global__ void __launch_bounds__(256) node_aggr3_k(const int* __restrict__ cnt, const unsigned short* __restrict__ csr,
                                                    const float* __restrict__ h3,
                                                    const float* __restrict__ a_s3, const float* __restrict__ a_d3,
                                                    const float* __restrict__ b3,
                                                    float* __restrict__ out, int N){
  int node = blockIdx.x * 32 + (threadIdx.x >> 3);
  if (node >= N) return;
  int q = threadIdx.x & 7;
  const int start = node << 6;
  int dg = cnt[node]; dg = dg < MAXDEG ? dg : MAXDEG;
  const int end = start + dg;
  const float a_s3v = a_s3[0];
  const float adv = a_d3[0] * h3[node];
  float s = 0.f, acc = 0.f;
  int i = start + q;
  if (i < end){
    int idx = csr[i];
    while (true){
      const int inext = i + 8;
      const bool more = inext < end;
      const int idxn = csr[more ? inext : i];
      float hv = h3[idx];
      float p = __expf(leaky(a_s3v * hv + adv));
      s += p; acc += hv * p;
      if (!more) break;
      idx = idxn; i = inext;
    }
  }
  #pragma unroll
  for (int off = 4; off; off >>= 1){
    s += __shfl_xor(s, off, 8);
    acc += __shfl_xor(acc, off, 8);
  }
  if (q == 0) out[node] = acc / s + b3[0];
}

// ---------------- launch ----------------
extern "C" void kernel_launch(void* const* d_in, const int* in_sizes, int n_in,
                              void* d_out, int out_size, void* d_ws, size_t ws_size,
                              hipStream_t stream){
  const float* x   = (const float*)d_in[0];
  const int*   ei  = (const int*)  d_in[1];
  const float* W1  = (const float*)d_in[2];
  const float* as1 = (const float*)d_in[3];
  const float* ad1 = (const float*)d_in[4];
  const float* b1  = (const float*)d_in[5];
  const float* W2  = (const float*)d_in[6];
  const float* as2 = (const float*)d_in[7];
  const float* ad2 = (const float*)d_in[8];
  const float* b2  = (const float*)d_in[9];
  const float* W3  = (const float*)d_in[10];
  const float* as3 = (const float*)d_in[11];
  const float* ad3 = (const float*)d_in[12];
  const float* b3  = (const float*)d_in[13];

  const int N    = in_sizes[0];       // IN_C = 1; N < 65536 required (ushort csr)
  const int Eg   = in_sizes[1] / 2;
  const int Etot = Eg + N;
  const int* esrc = ei;
  const int* edst = ei + Eg;

  char* w = (char*)d_ws;
  auto carve = [&](size_t bytes)->char*{
    char* p = w; w += (bytes + 15) & ~size_t(15); return p;
  };
  _Float16* hbuf = (_Float16*)carve((size_t)N * 128 * 2);  // fp16 head-major [4][N][32]
  float* asb    = (float*)carve((size_t)N * 4 * 4);   // head-major [4][N]
  float* adb    = (float*)carve((size_t)N * 4 * 4);   // head-major [4][N]
  float* h3b    = (float*)carve((size_t)N * 4);
  int*   cnt    = (int*)  carve((size_t)N * 4);
  unsigned short* csr16 = (unsigned short*)carve((size_t)N * MAXDEG * 2);  // bucketed

  const int B = 256;
  auto cdiv = [](int a, int b){ return (a + b - 1) / b; };

  // ---- CSR build: single atomic pass into fixed-stride buckets (XCD-partitioned) ----
  hipMemsetAsync(cnt, 0, (size_t)N * 4, stream);
  hipMemsetAsync(h3b, 0, (size_t)N * 4, stream);
  scatter_k<<<128 * 8, B, 0, stream>>>(esrc, edst, cnt, csr16, Eg, Etot, N);

  // ---- layers 1+2 fused: W staged once + r-prologue + dot2 matmul (no mid-loop barriers) ----
  gemm2_k<<<cdiv(N, 64), B, 0, stream>>>(cnt, csr16, x, as1, ad1, W1, b1,
                                         W2, as2, ad2, hbuf, asb, adb, N);
  // aggregate + fused layer-3 transform (writes h3 via atomics)
  node_aggr2_k<<<cdiv(N, 256) * 8, B, 0, stream>>>(cnt, csr16, asb, adb,
                                                   hbuf, b2, W3, h3b, N);

  // ---- layer 3 aggregate (H=1, C=1) ----
  node_aggr3_k<<<cdiv(N, 32), B, 0, stream>>>(cnt, csr16, h3b, as3, ad3, b3, (float*)d_out, N);
}